// Round 5
// baseline (334.889 us; speedup 1.0000x reference)
//
#include <hip/hip_runtime.h>

#define BB 512
#define TT 512
#define KK 64

typedef float v2f __attribute__((ext_vector_type(2)));

__device__ __forceinline__ float frl(float v, int lane) {
    return __int_as_float(__builtin_amdgcn_readlane(__float_as_int(v), lane));
}
__device__ __forceinline__ v2f vmax2(v2f a, v2f b) {
    v2f r; r.x = fmaxf(a.x, b.x); r.y = fmaxf(a.y, b.y); return r;
}
// wave-wide unsigned max; result valid in lane 63 (canonical gfx9 DPP sequence)
__device__ __forceinline__ unsigned wave_umax63(unsigned x) {
    unsigned d;
    d = (unsigned)__builtin_amdgcn_update_dpp((int)x, (int)x, 0x111, 0xF, 0xF, false); x = x > d ? x : d;
    d = (unsigned)__builtin_amdgcn_update_dpp((int)x, (int)x, 0x112, 0xF, 0xF, false); x = x > d ? x : d;
    d = (unsigned)__builtin_amdgcn_update_dpp((int)x, (int)x, 0x114, 0xF, 0xF, false); x = x > d ? x : d;
    d = (unsigned)__builtin_amdgcn_update_dpp((int)x, (int)x, 0x118, 0xF, 0xF, false); x = x > d ? x : d;
    d = (unsigned)__builtin_amdgcn_update_dpp((int)x, (int)x, 0x142, 0xA, 0xF, false); x = x > d ? x : d;
    d = (unsigned)__builtin_amdgcn_update_dpp((int)x, (int)x, 0x143, 0xC, 0xF, false); x = x > d ? x : d;
    return x;
}

// ---------------------------------------------------------------------------
// seq_lens[b] = nonzero_count >> 6 (fp32-exact in reference; proven R1-R4)
// ---------------------------------------------------------------------------
__global__ __launch_bounds__(256) void seqlen_kernel(const float* __restrict__ inp,
                                                     int* __restrict__ seq_lens) {
    int b = blockIdx.x;
    int tid = threadIdx.x;
    const float4* p4 = (const float4*)(inp + (size_t)b * TT * KK);
    const int n4 = TT * KK / 4;
    int cnt = 0;
    for (int idx = tid; idx < n4; idx += 256) {
        float4 v = p4[idx];
        cnt += (v.x != 0.0f) + (v.y != 0.0f) + (v.z != 0.0f) + (v.w != 0.0f);
    }
    #pragma unroll
    for (int off = 32; off > 0; off >>= 1) cnt += __shfl_down(cnt, off, 64);
    __shared__ int wsum[4];
    if ((tid & 63) == 0) wsum[tid >> 6] = cnt;
    __syncthreads();
    if (tid == 0) seq_lens[b] = (wsum[0] + wsum[1] + wsum[2] + wsum[3]) >> 6;
}

// ---------------------------------------------------------------------------
// Forward: max-only, alpha history to global ws. One wave per block.
// __launch_bounds__(64,1): min 1 wave/EU -> full VGPR budget so tc2 (64 VGPRs)
// stays register-resident (R4's VGPR_Count=52 proved it was spilled/reloaded).
// ---------------------------------------------------------------------------
#define FSTEP(PT, TC) do {                                                      \
    v2f av, a0, a1, a2, a3;                                                     \
    av.x = frl(alpha, 0); av.y = frl(alpha, 1); a0 = av + tc2[0];               \
    av.x = frl(alpha, 2); av.y = frl(alpha, 3); a1 = av + tc2[1];               \
    av.x = frl(alpha, 4); av.y = frl(alpha, 5); a2 = av + tc2[2];               \
    av.x = frl(alpha, 6); av.y = frl(alpha, 7); a3 = av + tc2[3];               \
    _Pragma("unroll")                                                           \
    for (int k = 4; k < 32; k += 4) {                                           \
        av.x = frl(alpha, 2*k+0); av.y = frl(alpha, 2*k+1); a0 = vmax2(a0, av + tc2[k+0]); \
        av.x = frl(alpha, 2*k+2); av.y = frl(alpha, 2*k+3); a1 = vmax2(a1, av + tc2[k+1]); \
        av.x = frl(alpha, 2*k+4); av.y = frl(alpha, 2*k+5); a2 = vmax2(a2, av + tc2[k+2]); \
        av.x = frl(alpha, 2*k+6); av.y = frl(alpha, 2*k+7); a3 = vmax2(a3, av + tc2[k+3]); \
    }                                                                           \
    v2f mm = vmax2(vmax2(a0, a1), vmax2(a2, a3));                               \
    float M = fmaxf(mm.x, mm.y);                                                \
    alpha = (TC) ? (PT + M) : alpha;                                            \
    *hp = alpha; hp += KK;                                                      \
} while (0)

__global__ __launch_bounds__(64, 1) void fwd_kernel(const float* __restrict__ pot,
                                                    const float* __restrict__ trans,
                                                    const int* __restrict__ seq_lens,
                                                    float* __restrict__ alphaH) {
    const int b = blockIdx.x;
    const int lane = threadIdx.x;

    // tc2[k] = {trans[2k][lane], trans[2k+1][lane]} -- 64 VGPRs, loop-invariant
    v2f tc2[32];
    #pragma unroll
    for (int k = 0; k < 32; ++k) {
        v2f t2; t2.x = trans[(2 * k) * KK + lane]; t2.y = trans[(2 * k + 1) * KK + lane];
        tc2[k] = t2;
    }

    const int seqlen = seq_lens[b];
    const float* pb = pot + (size_t)b * TT * KK;
    float* hb = alphaH + (size_t)b * TT * KK;

    float alpha = pb[lane];
    hb[lane] = alpha;
    float* hp = hb + KK + lane - lane;   // row base; store uses per-lane offset below
    hp = hb + KK + lane;                 // points at hb[t=1][lane]

    float pf[4] = { pb[1 * KK + lane], pb[2 * KK + lane], pb[3 * KK + lane], pb[4 * KK + lane] };
    const float* lp = pb + 5 * KK + lane;   // next row to prefetch (row 5)

    int t = 1;
    #pragma unroll 1
    for (int c = 0; c < 126; ++c) {          // t = 1..504; prefetches rows 5..508
        #pragma unroll
        for (int u = 0; u < 4; ++u) {
            FSTEP(pf[u], t < seqlen);
            pf[u] = *lp; lp += KK;
            ++t;
        }
    }
    // tail: pf holds rows 505..508; rows 509..511 loaded up front
    float e0 = pb[509 * KK + lane], e1 = pb[510 * KK + lane], e2 = pb[511 * KK + lane];
    FSTEP(pf[0], 505 < seqlen);
    FSTEP(pf[1], 506 < seqlen);
    FSTEP(pf[2], 507 < seqlen);
    FSTEP(pf[3], 508 < seqlen);
    FSTEP(e0, 509 < seqlen);
    FSTEP(e1, 510 < seqlen);
    FSTEP(e2, 511 < seqlen);
}

// ---------------------------------------------------------------------------
// Backtrace: exact recompute + DPP-max + ballot first-match (proven in R4).
// 2 waves/block, 2 batches/block sharing the transposed-trans LDS stage.
// ---------------------------------------------------------------------------
__global__ __launch_bounds__(128) void bt_kernel(const float* __restrict__ trans,
                                                 const int* __restrict__ seq_lens,
                                                 const float* __restrict__ alphaH,
                                                 int* __restrict__ out) {
    __shared__ float tT[KK][KK + 1];   // tT[j][i] = trans[i][j]

    const int lane = threadIdx.x & 63;
    const int w = threadIdx.x >> 6;
    const int b = blockIdx.x * 2 + w;

    for (int r = w * 32; r < w * 32 + 32; ++r) tT[lane][r] = trans[r * KK + lane];
    __syncthreads();

    const int seqlen = seq_lens[b];
    const float* hb = alphaH + (size_t)b * TT * KK;
    int* ob = out + b * TT;

    // final argmax over alpha[511] (first occurrence on ties)
    float alpha = hb[511 * KK + lane];
    float v = alpha; int idx = lane;
    #pragma unroll
    for (int off = 1; off < 64; off <<= 1) {
        float vo = __shfl_xor(v, off, 64);
        int io = __shfl_xor(idx, off, 64);
        bool take = (vo > v) || (vo == v && io < idx);
        v = take ? vo : v;
        idx = take ? io : idx;
    }
    int cur = idx;          // uniform
    int slot = cur;         // lane 63 slot survives as tag at t=511

    float r0 = hb[510 * KK + lane], r1 = hb[509 * KK + lane], r2 = hb[508 * KK + lane],
          r3 = hb[507 * KK + lane], r4 = hb[506 * KK + lane], r5 = hb[505 * KK + lane],
          r6 = hb[504 * KK + lane], r7 = hb[503 * KK + lane];

    auto bt_step = [&](int t, float arow) {
        if (t < seqlen) {   // uniform
            float cand = arow + tT[cur][lane];
            unsigned u = __float_as_uint(cand);
            u = u ^ ((unsigned)(((int)u) >> 31) | 0x80000000u);   // sortable key
            unsigned run = wave_umax63(u);
            unsigned Umax = (unsigned)__builtin_amdgcn_readlane((int)run, 63);
            unsigned long long mk = __ballot(u == Umax);
            cur = (int)__builtin_ctzll(mk);                        // first i == argmax
        }
        const int tm = t - 1;
        slot = ((tm & 63) == lane) ? cur : slot;
        if ((tm & 63) == 0) ob[tm + lane] = slot;
    };

    int T0 = 511;
    for (int c = 0; c < 63; ++c) {
        bt_step(T0 - 0, r0); { int pi = T0 - 9;  pi = pi < 0 ? 0 : pi; r0 = hb[pi * KK + lane]; }
        bt_step(T0 - 1, r1); { int pi = T0 - 10; pi = pi < 0 ? 0 : pi; r1 = hb[pi * KK + lane]; }
        bt_step(T0 - 2, r2); { int pi = T0 - 11; pi = pi < 0 ? 0 : pi; r2 = hb[pi * KK + lane]; }
        bt_step(T0 - 3, r3); { int pi = T0 - 12; pi = pi < 0 ? 0 : pi; r3 = hb[pi * KK + lane]; }
        bt_step(T0 - 4, r4); { int pi = T0 - 13; pi = pi < 0 ? 0 : pi; r4 = hb[pi * KK + lane]; }
        bt_step(T0 - 5, r5); { int pi = T0 - 14; pi = pi < 0 ? 0 : pi; r5 = hb[pi * KK + lane]; }
        bt_step(T0 - 6, r6); { int pi = T0 - 15; pi = pi < 0 ? 0 : pi; r6 = hb[pi * KK + lane]; }
        bt_step(T0 - 7, r7); { int pi = T0 - 16; pi = pi < 0 ? 0 : pi; r7 = hb[pi * KK + lane]; }
        T0 -= 8;
    }
    bt_step(7, r0); bt_step(6, r1); bt_step(5, r2); bt_step(4, r3);
    bt_step(3, r4); bt_step(2, r5); bt_step(1, r6);
}

// ---------------------------------------------------------------------------
// Fallback (proven R1 kernel) -- only if ws can't hold the alpha history.
// ---------------------------------------------------------------------------
__global__ __launch_bounds__(64) void viterbi_fallback(const float* __restrict__ pot,
                                                       const float* __restrict__ trans,
                                                       const int* __restrict__ seq_lens,
                                                       int* __restrict__ out) {
    __shared__ unsigned char bp[TT][KK];
    const int b = blockIdx.x;
    const int j = threadIdx.x;

    float tc[KK];
    #pragma unroll
    for (int i = 0; i < KK; ++i) tc[i] = trans[i * KK + j];

    const float* pb = pot + (size_t)b * TT * KK;
    float alpha = pb[j];
    const int seqlen = seq_lens[b];

    for (int t = 1; t < TT; ++t) {
        float ptj = pb[t * KK + j];
        float m[4]; int am[4];
        #pragma unroll
        for (int c = 0; c < 4; ++c) {
            const int i = c * 16;
            float ai = frl(alpha, i);
            m[c] = ai + tc[i];
            am[c] = i;
        }
        #pragma unroll
        for (int q = 1; q < 16; ++q) {
            #pragma unroll
            for (int c = 0; c < 4; ++c) {
                const int i = c * 16 + q;
                float ai = frl(alpha, i);
                float s = ai + tc[i];
                bool g = s > m[c];
                m[c] = g ? s : m[c];
                am[c] = g ? i : am[c];
            }
        }
        float M = m[0]; int BI = am[0];
        #pragma unroll
        for (int c = 1; c < 4; ++c) {
            bool g = m[c] > M;
            M = g ? m[c] : M;
            BI = g ? am[c] : BI;
        }
        const bool valid = (t < seqlen);
        alpha = valid ? (ptj + M) : alpha;
        bp[t][j] = (unsigned char)(valid ? BI : j);
    }

    float v = alpha; int idx = j;
    #pragma unroll
    for (int off = 1; off < 64; off <<= 1) {
        float vo = __shfl_xor(v, off, 64);
        int io = __shfl_xor(idx, off, 64);
        bool take = (vo > v) || (vo == v && io < idx);
        v = take ? vo : v;
        idx = take ? io : idx;
    }
    __syncthreads();
    if (j == 0) {
        int* ob = out + b * TT;
        int cur = idx;
        ob[TT - 1] = cur;
        for (int p = TT - 2; p >= 0; --p) {
            cur = bp[p + 1][cur];
            ob[p] = cur;
        }
    }
}

extern "C" void kernel_launch(void* const* d_in, const int* in_sizes, int n_in,
                              void* d_out, int out_size, void* d_ws, size_t ws_size,
                              hipStream_t stream) {
    const float* inp = (const float*)d_in[0];     // [B, T, K] fp32
    const float* trans = (const float*)d_in[1];   // [K, K] fp32
    int* out = (int*)d_out;                       // [B, T] int32

    const size_t histBytes = (size_t)BB * TT * KK * sizeof(float);  // 64 MB
    if (ws_size >= histBytes + 2048) {
        float* alphaH = (float*)d_ws;
        int* seq = (int*)((char*)d_ws + histBytes);
        seqlen_kernel<<<BB, 256, 0, stream>>>(inp, seq);
        fwd_kernel<<<BB, 64, 0, stream>>>(inp, trans, seq, alphaH);
        bt_kernel<<<BB / 2, 128, 0, stream>>>(trans, seq, alphaH, out);
    } else {
        int* seq = (int*)d_ws;
        seqlen_kernel<<<BB, 256, 0, stream>>>(inp, seq);
        viterbi_fallback<<<BB, KK, 0, stream>>>(inp, trans, seq, out);
    }
}

// Round 6
// 315.307 us; speedup vs baseline: 1.0621x; 1.0621x over previous
//
#include <hip/hip_runtime.h>

#define BB 512
#define TT 512
#define KK 64

typedef float v2f __attribute__((ext_vector_type(2)));

__device__ __forceinline__ float frl(float v, int lane) {
    return __int_as_float(__builtin_amdgcn_readlane(__float_as_int(v), lane));
}
__device__ __forceinline__ v2f vmax2(v2f a, v2f b) {
    v2f r; r.x = fmaxf(a.x, b.x); r.y = fmaxf(a.y, b.y); return r;
}
// wave-wide unsigned max; result valid in lane 63 (proven R4/R5)
__device__ __forceinline__ unsigned wave_umax63(unsigned x) {
    unsigned d;
    d = (unsigned)__builtin_amdgcn_update_dpp((int)x, (int)x, 0x111, 0xF, 0xF, false); x = x > d ? x : d;
    d = (unsigned)__builtin_amdgcn_update_dpp((int)x, (int)x, 0x112, 0xF, 0xF, false); x = x > d ? x : d;
    d = (unsigned)__builtin_amdgcn_update_dpp((int)x, (int)x, 0x114, 0xF, 0xF, false); x = x > d ? x : d;
    d = (unsigned)__builtin_amdgcn_update_dpp((int)x, (int)x, 0x118, 0xF, 0xF, false); x = x > d ? x : d;
    d = (unsigned)__builtin_amdgcn_update_dpp((int)x, (int)x, 0x142, 0xA, 0xF, false); x = x > d ? x : d;
    d = (unsigned)__builtin_amdgcn_update_dpp((int)x, (int)x, 0x143, 0xC, 0xF, false); x = x > d ? x : d;
    return x;
}

#define FSTEP(PT, TC) do {                                                      \
    v2f av, a0, a1, a2, a3;                                                     \
    av.x = frl(alpha, 0); av.y = frl(alpha, 1); a0 = av + tc2[0];               \
    av.x = frl(alpha, 2); av.y = frl(alpha, 3); a1 = av + tc2[1];               \
    av.x = frl(alpha, 4); av.y = frl(alpha, 5); a2 = av + tc2[2];               \
    av.x = frl(alpha, 6); av.y = frl(alpha, 7); a3 = av + tc2[3];               \
    _Pragma("unroll")                                                           \
    for (int k = 4; k < 32; k += 4) {                                           \
        av.x = frl(alpha, 2*k+0); av.y = frl(alpha, 2*k+1); a0 = vmax2(a0, av + tc2[k+0]); \
        av.x = frl(alpha, 2*k+2); av.y = frl(alpha, 2*k+3); a1 = vmax2(a1, av + tc2[k+1]); \
        av.x = frl(alpha, 2*k+4); av.y = frl(alpha, 2*k+5); a2 = vmax2(a2, av + tc2[k+2]); \
        av.x = frl(alpha, 2*k+6); av.y = frl(alpha, 2*k+7); a3 = vmax2(a3, av + tc2[k+3]); \
    }                                                                           \
    v2f mm = vmax2(vmax2(a0, a1), vmax2(a2, a3));                               \
    float M = fmaxf(mm.x, mm.y);                                                \
    alpha = (TC) ? (PT + M) : alpha;                                            \
    *hp = alpha; hp += KK;                                                      \
} while (0)

// ---------------------------------------------------------------------------
// Fused: count -> max-only forward (alpha history to ws) -> DPP/ballot
// backtrace. One wave per batch, zero inter-wave communication, 1 dispatch.
// ---------------------------------------------------------------------------
__global__ __launch_bounds__(64, 1) void crf_fused(const float* __restrict__ pot,
                                                   const float* __restrict__ trans,
                                                   float* __restrict__ alphaH,
                                                   int* __restrict__ out) {
    __shared__ float tT[KK][KK + 1];   // tT[j][i] = trans[i][j] (2-way alias: free)

    const int b = blockIdx.x;
    const int lane = threadIdx.x;
    const float* pb = pot + (size_t)b * TT * KK;
    float* hb = alphaH + (size_t)b * TT * KK;
    int* ob = out + b * TT;

    // ---- seq_len: count this batch's nonzeros (warms L2/L3 for pot) ----
    int cnt = 0;
    {
        const float4* p4 = (const float4*)pb;
        #pragma unroll 4
        for (int r = 0; r < 128; ++r) {
            float4 v = p4[lane + 64 * r];
            cnt += (v.x != 0.f) + (v.y != 0.f) + (v.z != 0.f) + (v.w != 0.f);
        }
        #pragma unroll
        for (int off = 32; off > 0; off >>= 1) cnt += __shfl_xor(cnt, off, 64);
    }
    const int seqlen = cnt >> 6;   // trunc(mean) — fp32-exact per R1

    // ---- stage transposed trans for backtrace (same wave: no barrier) ----
    #pragma unroll 8
    for (int r = 0; r < KK; ++r) tT[lane][r] = trans[r * KK + lane];

    // ---- tc2[k] = {trans[2k][lane], trans[2k+1][lane]}; pin vs remat ----
    v2f tc2[32];
    #pragma unroll
    for (int k = 0; k < 32; ++k) {
        v2f t2; t2.x = trans[(2 * k) * KK + lane]; t2.y = trans[(2 * k + 1) * KK + lane];
        tc2[k] = t2;
    }
    #pragma unroll
    for (int k = 0; k < 32; ++k) asm volatile("" : "+v"(tc2[k]));  // opaque: no remat

    // ------------------------------ forward ------------------------------
    float alpha = pb[lane];
    hb[lane] = alpha;
    float* hp = hb + KK + lane;

    float pf[4] = { pb[1 * KK + lane], pb[2 * KK + lane], pb[3 * KK + lane], pb[4 * KK + lane] };
    const float* lp = pb + 5 * KK + lane;

    int t = 1;
    #pragma unroll 1
    for (int c = 0; c < 126; ++c) {          // t = 1..504
        #pragma unroll
        for (int u = 0; u < 4; ++u) {
            FSTEP(pf[u], t < seqlen);
            pf[u] = *lp; lp += KK;
            ++t;
        }
    }
    float e0 = pb[509 * KK + lane], e1 = pb[510 * KK + lane], e2 = pb[511 * KK + lane];
    FSTEP(pf[0], 505 < seqlen);
    FSTEP(pf[1], 506 < seqlen);
    FSTEP(pf[2], 507 < seqlen);
    FSTEP(pf[3], 508 < seqlen);
    FSTEP(e0, 509 < seqlen);
    FSTEP(e1, 510 < seqlen);
    FSTEP(e2, 511 < seqlen);

    asm volatile("s_waitcnt vmcnt(0)" ::: "memory");   // alpha history visible to our loads

    // ---- final argmax over live alpha (first occurrence on ties) ----
    float v = alpha; int idx = lane;
    #pragma unroll
    for (int off = 1; off < 64; off <<= 1) {
        float vo = __shfl_xor(v, off, 64);
        int io = __shfl_xor(idx, off, 64);
        bool take = (vo > v) || (vo == v && io < idx);
        v = take ? vo : v;
        idx = take ? io : idx;
    }
    int cur = idx;          // uniform
    int slot = cur;         // lane 63 slot survives as tag at t=511

    // ---- backtrace: recompute + DPP-max + ballot first-match (proven) ----
    float r0 = hb[510 * KK + lane], r1 = hb[509 * KK + lane], r2 = hb[508 * KK + lane],
          r3 = hb[507 * KK + lane], r4 = hb[506 * KK + lane], r5 = hb[505 * KK + lane],
          r6 = hb[504 * KK + lane], r7 = hb[503 * KK + lane];

    auto bt_step = [&](int tt, float arow) {
        if (tt < seqlen) {   // uniform
            float cand = arow + tT[cur][lane];
            unsigned u = __float_as_uint(cand);
            u = u ^ ((unsigned)(((int)u) >> 31) | 0x80000000u);   // sortable key
            unsigned run = wave_umax63(u);
            unsigned Umax = (unsigned)__builtin_amdgcn_readlane((int)run, 63);
            unsigned long long mk = __ballot(u == Umax);
            cur = (int)__builtin_ctzll(mk);                        // first i == argmax
        }
        const int tm = tt - 1;
        slot = ((tm & 63) == lane) ? cur : slot;
        if ((tm & 63) == 0) ob[tm + lane] = slot;
    };

    int T0 = 511;
    for (int c = 0; c < 63; ++c) {
        bt_step(T0 - 0, r0); { int pi = T0 - 9;  pi = pi < 0 ? 0 : pi; r0 = hb[pi * KK + lane]; }
        bt_step(T0 - 1, r1); { int pi = T0 - 10; pi = pi < 0 ? 0 : pi; r1 = hb[pi * KK + lane]; }
        bt_step(T0 - 2, r2); { int pi = T0 - 11; pi = pi < 0 ? 0 : pi; r2 = hb[pi * KK + lane]; }
        bt_step(T0 - 3, r3); { int pi = T0 - 12; pi = pi < 0 ? 0 : pi; r3 = hb[pi * KK + lane]; }
        bt_step(T0 - 4, r4); { int pi = T0 - 13; pi = pi < 0 ? 0 : pi; r4 = hb[pi * KK + lane]; }
        bt_step(T0 - 5, r5); { int pi = T0 - 14; pi = pi < 0 ? 0 : pi; r5 = hb[pi * KK + lane]; }
        bt_step(T0 - 6, r6); { int pi = T0 - 15; pi = pi < 0 ? 0 : pi; r6 = hb[pi * KK + lane]; }
        bt_step(T0 - 7, r7); { int pi = T0 - 16; pi = pi < 0 ? 0 : pi; r7 = hb[pi * KK + lane]; }
        T0 -= 8;
    }
    bt_step(7, r0); bt_step(6, r1); bt_step(5, r2); bt_step(4, r3);
    bt_step(3, r4); bt_step(2, r5); bt_step(1, r6);
}

// ---------------------------------------------------------------------------
// Fallback path (proven R1 kernels) -- only if ws can't hold alpha history.
// ---------------------------------------------------------------------------
__global__ __launch_bounds__(256) void seqlen_kernel(const float* __restrict__ inp,
                                                     int* __restrict__ seq_lens) {
    int b = blockIdx.x;
    int tid = threadIdx.x;
    const float4* p4 = (const float4*)(inp + (size_t)b * TT * KK);
    const int n4 = TT * KK / 4;
    int cnt = 0;
    for (int idx = tid; idx < n4; idx += 256) {
        float4 v = p4[idx];
        cnt += (v.x != 0.0f) + (v.y != 0.0f) + (v.z != 0.0f) + (v.w != 0.0f);
    }
    #pragma unroll
    for (int off = 32; off > 0; off >>= 1) cnt += __shfl_down(cnt, off, 64);
    __shared__ int wsum[4];
    if ((tid & 63) == 0) wsum[tid >> 6] = cnt;
    __syncthreads();
    if (tid == 0) seq_lens[b] = (wsum[0] + wsum[1] + wsum[2] + wsum[3]) >> 6;
}

__global__ __launch_bounds__(64) void viterbi_fallback(const float* __restrict__ pot,
                                                       const float* __restrict__ trans,
                                                       const int* __restrict__ seq_lens,
                                                       int* __restrict__ out) {
    __shared__ unsigned char bp[TT][KK];
    const int b = blockIdx.x;
    const int j = threadIdx.x;

    float tc[KK];
    #pragma unroll
    for (int i = 0; i < KK; ++i) tc[i] = trans[i * KK + j];

    const float* pb = pot + (size_t)b * TT * KK;
    float alpha = pb[j];
    const int seqlen = seq_lens[b];

    for (int t = 1; t < TT; ++t) {
        float ptj = pb[t * KK + j];
        float m[4]; int am[4];
        #pragma unroll
        for (int c = 0; c < 4; ++c) {
            const int i = c * 16;
            float ai = frl(alpha, i);
            m[c] = ai + tc[i];
            am[c] = i;
        }
        #pragma unroll
        for (int q = 1; q < 16; ++q) {
            #pragma unroll
            for (int c = 0; c < 4; ++c) {
                const int i = c * 16 + q;
                float ai = frl(alpha, i);
                float s = ai + tc[i];
                bool g = s > m[c];
                m[c] = g ? s : m[c];
                am[c] = g ? i : am[c];
            }
        }
        float M = m[0]; int BI = am[0];
        #pragma unroll
        for (int c = 1; c < 4; ++c) {
            bool g = m[c] > M;
            M = g ? m[c] : M;
            BI = g ? am[c] : BI;
        }
        const bool valid = (t < seqlen);
        alpha = valid ? (ptj + M) : alpha;
        bp[t][j] = (unsigned char)(valid ? BI : j);
    }

    float v = alpha; int idx = j;
    #pragma unroll
    for (int off = 1; off < 64; off <<= 1) {
        float vo = __shfl_xor(v, off, 64);
        int io = __shfl_xor(idx, off, 64);
        bool take = (vo > v) || (vo == v && io < idx);
        v = take ? vo : v;
        idx = take ? io : idx;
    }
    __syncthreads();
    if (j == 0) {
        int* ob = out + b * TT;
        int cur = idx;
        ob[TT - 1] = cur;
        for (int p = TT - 2; p >= 0; --p) {
            cur = bp[p + 1][cur];
            ob[p] = cur;
        }
    }
}

extern "C" void kernel_launch(void* const* d_in, const int* in_sizes, int n_in,
                              void* d_out, int out_size, void* d_ws, size_t ws_size,
                              hipStream_t stream) {
    const float* inp = (const float*)d_in[0];     // [B, T, K] fp32
    const float* trans = (const float*)d_in[1];   // [K, K] fp32
    int* out = (int*)d_out;                       // [B, T] int32

    const size_t histBytes = (size_t)BB * TT * KK * sizeof(float);  // 64 MB
    if (ws_size >= histBytes) {
        float* alphaH = (float*)d_ws;
        crf_fused<<<BB, 64, 0, stream>>>(inp, trans, alphaH, out);
    } else {
        int* seq = (int*)d_ws;
        seqlen_kernel<<<BB, 256, 0, stream>>>(inp, seq);
        viterbi_fallback<<<BB, KK, 0, stream>>>(inp, trans, seq, out);
    }
}

// Round 7
// 282.418 us; speedup vs baseline: 1.1858x; 1.1165x over previous
//
#include <hip/hip_runtime.h>

#define BB 512
#define TT 512
#define KK 64

typedef float v2f __attribute__((ext_vector_type(2)));

__device__ __forceinline__ float frl(float v, int lane) {
    return __int_as_float(__builtin_amdgcn_readlane(__float_as_int(v), lane));
}
__device__ __forceinline__ v2f vmax2(v2f a, v2f b) {
    v2f r; r.x = fmaxf(a.x, b.x); r.y = fmaxf(a.y, b.y); return r;
}
// wave-wide unsigned max; result valid in lane 63 (proven R4-R6)
__device__ __forceinline__ unsigned wave_umax63(unsigned x) {
    unsigned d;
    d = (unsigned)__builtin_amdgcn_update_dpp((int)x, (int)x, 0x111, 0xF, 0xF, false); x = x > d ? x : d;
    d = (unsigned)__builtin_amdgcn_update_dpp((int)x, (int)x, 0x112, 0xF, 0xF, false); x = x > d ? x : d;
    d = (unsigned)__builtin_amdgcn_update_dpp((int)x, (int)x, 0x114, 0xF, 0xF, false); x = x > d ? x : d;
    d = (unsigned)__builtin_amdgcn_update_dpp((int)x, (int)x, 0x118, 0xF, 0xF, false); x = x > d ? x : d;
    d = (unsigned)__builtin_amdgcn_update_dpp((int)x, (int)x, 0x142, 0xA, 0xF, false); x = x > d ? x : d;
    d = (unsigned)__builtin_amdgcn_update_dpp((int)x, (int)x, 0x143, 0xC, 0xF, false); x = x > d ? x : d;
    return x;
}

// One Viterbi step via LDS broadcast (replaces 64 v_readlane: ~8cyc each, the
// R1-R6 bottleneck). DS ops are in-order within a wave -> clobber, no barrier.
#define FSTEP(PT, TC) do {                                                      \
    la[lane] = alpha;                                                           \
    asm volatile("" ::: "memory");                                              \
    v2f acc0, acc1, acc2, acc3;                                                 \
    {                                                                           \
        float4 a4 = ((float4*)la)[0];                                           \
        v2f lo; lo.x = a4.x; lo.y = a4.y; acc0 = lo + tcl[0];                   \
        v2f hi; hi.x = a4.z; hi.y = a4.w; acc1 = hi + tch[0];                   \
        a4 = ((float4*)la)[1];                                                  \
        lo.x = a4.x; lo.y = a4.y; acc2 = lo + tcl[1];                           \
        hi.x = a4.z; hi.y = a4.w; acc3 = hi + tch[1];                           \
    }                                                                           \
    _Pragma("unroll")                                                           \
    for (int c = 2; c < 16; c += 2) {                                           \
        float4 a4 = ((float4*)la)[c];                                           \
        v2f lo; lo.x = a4.x; lo.y = a4.y; acc0 = vmax2(acc0, lo + tcl[c]);      \
        v2f hi; hi.x = a4.z; hi.y = a4.w; acc1 = vmax2(acc1, hi + tch[c]);      \
        a4 = ((float4*)la)[c + 1];                                              \
        lo.x = a4.x; lo.y = a4.y; acc2 = vmax2(acc2, lo + tcl[c + 1]);          \
        hi.x = a4.z; hi.y = a4.w; acc3 = vmax2(acc3, hi + tch[c + 1]);          \
    }                                                                           \
    v2f mm = vmax2(vmax2(acc0, acc1), vmax2(acc2, acc3));                       \
    float M = fmaxf(mm.x, mm.y);                                                \
    alpha = (TC) ? (PT + M) : alpha;                                            \
    *hp = alpha; hp += KK;                                                      \
} while (0)

// ---------------------------------------------------------------------------
// Fused: count -> max-only forward (alpha history to ws) -> DPP/ballot
// backtrace. One wave per batch, 1 dispatch.
// ---------------------------------------------------------------------------
__global__ __launch_bounds__(64, 1) void crf_fused(const float* __restrict__ pot,
                                                   const float* __restrict__ trans,
                                                   float* __restrict__ alphaH,
                                                   int* __restrict__ out) {
    __shared__ float tT[KK][KK + 1];   // tT[j][i] = trans[i][j] (backtrace)
    __shared__ float la[KK];           // alpha broadcast buffer (uniform reads)

    const int b = blockIdx.x;
    const int lane = threadIdx.x;
    const float* pb = pot + (size_t)b * TT * KK;
    float* hb = alphaH + (size_t)b * TT * KK;
    int* ob = out + b * TT;

    // ---- seq_len: count this batch's nonzeros (warms L2/L3 for pot) ----
    int cnt = 0;
    {
        const float4* p4 = (const float4*)pb;
        #pragma unroll 4
        for (int r = 0; r < 128; ++r) {
            float4 v = p4[lane + 64 * r];
            cnt += (v.x != 0.f) + (v.y != 0.f) + (v.z != 0.f) + (v.w != 0.f);
        }
        #pragma unroll
        for (int off = 32; off > 0; off >>= 1) cnt += __shfl_xor(cnt, off, 64);
    }
    const int seqlen = cnt >> 6;   // trunc(mean) — fp32-exact per R1

    // ---- stage transposed trans for backtrace (same wave: no barrier) ----
    #pragma unroll 8
    for (int r = 0; r < KK; ++r) tT[lane][r] = trans[r * KK + lane];

    // ---- trans column 'lane' as v2f pairs; pin vs remat (proven R6) ----
    v2f tcl[16], tch[16];   // tcl[c] = rows 4c,4c+1; tch[c] = rows 4c+2,4c+3
    #pragma unroll
    for (int c = 0; c < 16; ++c) {
        v2f l2, h2;
        l2.x = trans[(4 * c + 0) * KK + lane]; l2.y = trans[(4 * c + 1) * KK + lane];
        h2.x = trans[(4 * c + 2) * KK + lane]; h2.y = trans[(4 * c + 3) * KK + lane];
        tcl[c] = l2; tch[c] = h2;
    }
    #pragma unroll
    for (int c = 0; c < 16; ++c) {
        asm volatile("" : "+v"(tcl[c]));
        asm volatile("" : "+v"(tch[c]));
    }

    // ------------------------------ forward ------------------------------
    float alpha = pb[lane];
    hb[lane] = alpha;
    float* hp = hb + KK + lane;

    float pf[4] = { pb[1 * KK + lane], pb[2 * KK + lane], pb[3 * KK + lane], pb[4 * KK + lane] };
    const float* lp = pb + 5 * KK + lane;

    int t = 1;
    #pragma unroll 1
    for (int c = 0; c < 126; ++c) {          // t = 1..504
        #pragma unroll
        for (int u = 0; u < 4; ++u) {
            FSTEP(pf[u], t < seqlen);
            pf[u] = *lp; lp += KK;
            ++t;
        }
    }
    float e0 = pb[509 * KK + lane], e1 = pb[510 * KK + lane], e2 = pb[511 * KK + lane];
    FSTEP(pf[0], 505 < seqlen);
    FSTEP(pf[1], 506 < seqlen);
    FSTEP(pf[2], 507 < seqlen);
    FSTEP(pf[3], 508 < seqlen);
    FSTEP(e0, 509 < seqlen);
    FSTEP(e1, 510 < seqlen);
    FSTEP(e2, 511 < seqlen);

    asm volatile("s_waitcnt vmcnt(0)" ::: "memory");   // alpha history visible to our loads

    // ---- final argmax over live alpha (first occurrence on ties) ----
    float v = alpha; int idx = lane;
    #pragma unroll
    for (int off = 1; off < 64; off <<= 1) {
        float vo = __shfl_xor(v, off, 64);
        int io = __shfl_xor(idx, off, 64);
        bool take = (vo > v) || (vo == v && io < idx);
        v = take ? vo : v;
        idx = take ? io : idx;
    }
    int cur = idx;          // uniform
    int slot = cur;         // lane 63 slot survives as tag at t=511

    // ---- backtrace: recompute + DPP-max + ballot first-match (proven) ----
    float r0 = hb[510 * KK + lane], r1 = hb[509 * KK + lane], r2 = hb[508 * KK + lane],
          r3 = hb[507 * KK + lane], r4 = hb[506 * KK + lane], r5 = hb[505 * KK + lane],
          r6 = hb[504 * KK + lane], r7 = hb[503 * KK + lane];

    auto bt_step = [&](int tt, float arow) {
        if (tt < seqlen) {   // uniform
            float cand = arow + tT[cur][lane];
            unsigned u = __float_as_uint(cand);
            u = u ^ ((unsigned)(((int)u) >> 31) | 0x80000000u);   // sortable key
            unsigned run = wave_umax63(u);
            unsigned Umax = (unsigned)__builtin_amdgcn_readlane((int)run, 63);
            unsigned long long mk = __ballot(u == Umax);
            cur = (int)__builtin_ctzll(mk);                        // first i == argmax
        }
        const int tm = tt - 1;
        slot = ((tm & 63) == lane) ? cur : slot;
        if ((tm & 63) == 0) ob[tm + lane] = slot;
    };

    int T0 = 511;
    for (int c = 0; c < 63; ++c) {
        bt_step(T0 - 0, r0); { int pi = T0 - 9;  pi = pi < 0 ? 0 : pi; r0 = hb[pi * KK + lane]; }
        bt_step(T0 - 1, r1); { int pi = T0 - 10; pi = pi < 0 ? 0 : pi; r1 = hb[pi * KK + lane]; }
        bt_step(T0 - 2, r2); { int pi = T0 - 11; pi = pi < 0 ? 0 : pi; r2 = hb[pi * KK + lane]; }
        bt_step(T0 - 3, r3); { int pi = T0 - 12; pi = pi < 0 ? 0 : pi; r3 = hb[pi * KK + lane]; }
        bt_step(T0 - 4, r4); { int pi = T0 - 13; pi = pi < 0 ? 0 : pi; r4 = hb[pi * KK + lane]; }
        bt_step(T0 - 5, r5); { int pi = T0 - 14; pi = pi < 0 ? 0 : pi; r5 = hb[pi * KK + lane]; }
        bt_step(T0 - 6, r6); { int pi = T0 - 15; pi = pi < 0 ? 0 : pi; r6 = hb[pi * KK + lane]; }
        bt_step(T0 - 7, r7); { int pi = T0 - 16; pi = pi < 0 ? 0 : pi; r7 = hb[pi * KK + lane]; }
        T0 -= 8;
    }
    bt_step(7, r0); bt_step(6, r1); bt_step(5, r2); bt_step(4, r3);
    bt_step(3, r4); bt_step(2, r5); bt_step(1, r6);
}

// ---------------------------------------------------------------------------
// Fallback path (proven R1 kernels) -- only if ws can't hold alpha history.
// ---------------------------------------------------------------------------
__global__ __launch_bounds__(256) void seqlen_kernel(const float* __restrict__ inp,
                                                     int* __restrict__ seq_lens) {
    int b = blockIdx.x;
    int tid = threadIdx.x;
    const float4* p4 = (const float4*)(inp + (size_t)b * TT * KK);
    const int n4 = TT * KK / 4;
    int cnt = 0;
    for (int idx = tid; idx < n4; idx += 256) {
        float4 v = p4[idx];
        cnt += (v.x != 0.0f) + (v.y != 0.0f) + (v.z != 0.0f) + (v.w != 0.0f);
    }
    #pragma unroll
    for (int off = 32; off > 0; off >>= 1) cnt += __shfl_down(cnt, off, 64);
    __shared__ int wsum[4];
    if ((tid & 63) == 0) wsum[tid >> 6] = cnt;
    __syncthreads();
    if (tid == 0) seq_lens[b] = (wsum[0] + wsum[1] + wsum[2] + wsum[3]) >> 6;
}

__global__ __launch_bounds__(64) void viterbi_fallback(const float* __restrict__ pot,
                                                       const float* __restrict__ trans,
                                                       const int* __restrict__ seq_lens,
                                                       int* __restrict__ out) {
    __shared__ unsigned char bp[TT][KK];
    const int b = blockIdx.x;
    const int j = threadIdx.x;

    float tc[KK];
    #pragma unroll
    for (int i = 0; i < KK; ++i) tc[i] = trans[i * KK + j];

    const float* pb = pot + (size_t)b * TT * KK;
    float alpha = pb[j];
    const int seqlen = seq_lens[b];

    for (int t = 1; t < TT; ++t) {
        float ptj = pb[t * KK + j];
        float m[4]; int am[4];
        #pragma unroll
        for (int c = 0; c < 4; ++c) {
            const int i = c * 16;
            float ai = frl(alpha, i);
            m[c] = ai + tc[i];
            am[c] = i;
        }
        #pragma unroll
        for (int q = 1; q < 16; ++q) {
            #pragma unroll
            for (int c = 0; c < 4; ++c) {
                const int i = c * 16 + q;
                float ai = frl(alpha, i);
                float s = ai + tc[i];
                bool g = s > m[c];
                m[c] = g ? s : m[c];
                am[c] = g ? i : am[c];
            }
        }
        float M = m[0]; int BI = am[0];
        #pragma unroll
        for (int c = 1; c < 4; ++c) {
            bool g = m[c] > M;
            M = g ? m[c] : M;
            BI = g ? am[c] : BI;
        }
        const bool valid = (t < seqlen);
        alpha = valid ? (ptj + M) : alpha;
        bp[t][j] = (unsigned char)(valid ? BI : j);
    }

    float v = alpha; int idx = j;
    #pragma unroll
    for (int off = 1; off < 64; off <<= 1) {
        float vo = __shfl_xor(v, off, 64);
        int io = __shfl_xor(idx, off, 64);
        bool take = (vo > v) || (vo == v && io < idx);
        v = take ? vo : v;
        idx = take ? io : idx;
    }
    __syncthreads();
    if (j == 0) {
        int* ob = out + b * TT;
        int cur = idx;
        ob[TT - 1] = cur;
        for (int p = TT - 2; p >= 0; --p) {
            cur = bp[p + 1][cur];
            ob[p] = cur;
        }
    }
}

extern "C" void kernel_launch(void* const* d_in, const int* in_sizes, int n_in,
                              void* d_out, int out_size, void* d_ws, size_t ws_size,
                              hipStream_t stream) {
    const float* inp = (const float*)d_in[0];     // [B, T, K] fp32
    const float* trans = (const float*)d_in[1];   // [K, K] fp32
    int* out = (int*)d_out;                       // [B, T] int32

    const size_t histBytes = (size_t)BB * TT * KK * sizeof(float);  // 64 MB
    if (ws_size >= histBytes) {
        float* alphaH = (float*)d_ws;
        crf_fused<<<BB, 64, 0, stream>>>(inp, trans, alphaH, out);
    } else {
        int* seq = (int*)d_ws;
        seqlen_kernel<<<BB, 256, 0, stream>>>(inp, seq);
        viterbi_fallback<<<BB, KK, 0, stream>>>(inp, trans, seq, out);
    }
}